// Round 20
// baseline (202.584 us; speedup 1.0000x reference)
//
#include <hip/hip_runtime.h>
#include <hip/hip_bf16.h>

#define KP   208        // padded K
#define MAXFRAG 256
#define GAP_THR 2e-4
#define NSLICE 2
#define PT_BYTES 26624  // gemm1: per c-tile 208 rows * 128 B (hi|lo swizzled)
#define BUF_B 31744     // gemm1 per-buffer LDS bytes (x hi/lo + proto tile)

typedef __attribute__((ext_vector_type(8))) short short8v;  // 8 bf16
typedef __attribute__((ext_vector_type(4))) float f32x4;

// byte address of element (row, k) in a 64-row x 256-k swizzled bf16 tile set
__device__ __forceinline__ size_t tb_addr(int row, int k) {
  const int tile = row >> 6, r = row & 63, q = k >> 3, e = k & 7;
  return (size_t)tile * 32768 + (size_t)r * 512 +
         (size_t)((((q * 16) ^ ((r & 7) << 4))) + e * 2);
}

// ---------------------------------------------------------------------------
__device__ __forceinline__ double row_norm(const float* v, int C, int tid) {
  double ss = 0.0;
  for (int c = tid; c < C; c += 256) { double t = (double)v[c]; ss = fma(t, t, ss); }
  __shared__ double red[4];
  for (int m = 32; m >= 1; m >>= 1) ss += __shfl_xor(ss, m, 64);
  if ((tid & 63) == 0) red[tid >> 6] = ss;
  __syncthreads();
  double s = red[0] + red[1] + red[2] + red[3];
  double n = sqrt(s);
  return (n < 1e-12) ? 1e-12 : n;
}

// ---------------------------------------------------------------------------
// FUSED l2-normalize: one pass over concepts writes BOTH the swizzled bf16
// hi/lo tiles (gemm1) and the fp64 concept-major proto (recompute path).
// ---------------------------------------------------------------------------
__global__ __launch_bounds__(256) void l2norm_all_kernel(
    const float* __restrict__ concepts, short* __restrict__ ptile,
    double* __restrict__ pt64k, int C, int K) {
  int k = blockIdx.x;  // 0..KP-1
  char* pk = (char*)ptile + (size_t)k * 128;
  if (k >= K) {
    for (int c = threadIdx.x; c < C; c += 256) {
      int ct = c >> 5, cin = c & 31, q = cin >> 3, e = cin & 7;
      char* base = pk + (size_t)ct * PT_BYTES;
      *(short*)(base + (((q * 16) ^ ((k & 7) << 4)) + e * 2)) = 0;
      *(short*)(base + (((q * 16 + 64) ^ ((k & 7) << 4)) + e * 2)) = 0;
      pt64k[(size_t)k * C + c] = 0.0;
    }
    return;
  }
  const float* v = concepts + (size_t)k * C;
  double n = row_norm(v, C, threadIdx.x);
  for (int c = threadIdx.x; c < C; c += 256) {
    double pv = (double)v[c] / n;
    pt64k[(size_t)k * C + c] = pv;
    float f = (float)pv;
    __hip_bfloat16 hb = __float2bfloat16(f);
    float hf = __bfloat162float(hb);
    __hip_bfloat16 lb = __float2bfloat16(f - hf);
    int ct = c >> 5, cin = c & 31, q = cin >> 3, e = cin & 7;
    char* base = pk + (size_t)ct * PT_BYTES;
    *(short*)(base + (((q * 16) ^ ((k & 7) << 4)) + e * 2)) = *(short*)&hb;
    *(short*)(base + (((q * 16 + 64) ^ ((k & 7) << 4)) + e * 2)) = *(short*)&lb;
  }
}

// fcw -> bf16 swizzled tile-major; also zeroes fragcnt (fused zc)
__global__ __launch_bounds__(256) void fcw_bf16_kernel(
    const float* __restrict__ fcw, char* __restrict__ fcwb,
    int* __restrict__ fragcnt, int K, int NC) {
  int idx = blockIdx.x * 256 + threadIdx.x;
  if (idx == 0) *fragcnt = 0;
  int col = idx >> 8, k = idx & 255;
  float v = (col < NC && k < K) ? fcw[(size_t)col * K + k] : 0.f;
  __hip_bfloat16 hb = __float2bfloat16(v);
  *(short*)(fcwb + tb_addr(col, k)) = *(short*)&hb;
}

// ---------------------------------------------------------------------------
// Phase-1 GEMM1 partial: bf16-split MFMA over one C-slice.
// 2-PHASE DOUBLE-BUFFERED: stage(it+1) issued BEFORE compute(it); one
// barrier per iteration (its vmcnt(0) drain lands after compute hid latency).
// LDS 2 x 31744 B -> 2 blocks/CU.
// ---------------------------------------------------------------------------
__global__ __launch_bounds__(256, 2) void gemm1_mfma_partial_kernel(
    const float* __restrict__ x, const short* __restrict__ ptile,
    float* __restrict__ pfeat, int B, int C, int cslice) {
  __shared__ __align__(16) char smem[2 * BUF_B];  // 63,488 B
  float* ps = (float*)smem;  // epilogue alias [32][212]

  const int t = threadIdx.x;
  const int lane = t & 63;
  const int w = t >> 6;
  const int wr = w & 1, wc = w >> 1;
  const int lm = lane & 15;
  const int quad = (lane >> 4) * 16;
  const int r0 = blockIdx.x * 32;
  const int sl = blockIdx.y;
  const int nct = wc ? 6 : 7;
  const int ct0 = wc ? 7 : 0;
  const int ct_base = sl * (cslice >> 5);

  f32x4 acc[7];
#pragma unroll
  for (int j = 0; j < 7; ++j) acc[j] = (f32x4)(0.0f);

  const int xrow = t >> 3, xc4 = (t & 7) * 4;
  const float* xbase = &x[(size_t)(r0 + xrow) * C + sl * cslice + xc4];

  const int c_lo = (w == 0) ? 0 : (w == 1) ? 7 : (w == 2) ? 14 : 20;
  const int c_hi = (w == 0) ? 7 : (w == 1) ? 14 : (w == 2) ? 20 : 26;

  const int NIT = cslice >> 5;  // 32

  auto stage = [&](int bufi, int it, float4 xv) {
    char* base = smem + bufi * BUF_B;
    short* xh = (short*)base;
    short* xl = (short*)(base + 2560);
    char* pt = base + 5120;
    // proto glds (issue first: longest latency)
    const char* gsrc = (const char*)ptile + (size_t)(ct_base + it) * PT_BYTES;
    for (int cc = c_lo; cc < c_hi; ++cc)
      __builtin_amdgcn_global_load_lds(
          (const __attribute__((address_space(1))) unsigned int*)(gsrc + cc * 1024 + lane * 16),
          (__attribute__((address_space(3))) unsigned int*)(pt + cc * 1024),
          16, 0, 0);
    // x hi/lo split
    short h[4], l[4];
#pragma unroll
    for (int e = 0; e < 4; ++e) {
      float f = (&xv.x)[e];
      __hip_bfloat16 hb = __float2bfloat16(f);
      float hf = __bfloat162float(hb);
      __hip_bfloat16 lb = __float2bfloat16(f - hf);
      h[e] = *(short*)&hb;
      l[e] = *(short*)&lb;
    }
    *(short4*)&xh[xrow * 40 + xc4] = make_short4(h[0], h[1], h[2], h[3]);
    *(short4*)&xl[xrow * 40 + xc4] = make_short4(l[0], l[1], l[2], l[3]);
  };

  float4 xcur = *(const float4*)xbase;
  float4 xnxt;
  stage(0, 0, xcur);
  if (NIT > 1) xnxt = *(const float4*)(xbase + 32);
  __syncthreads();

  for (int it = 0; it < NIT; ++it) {
    const int cur = it & 1;
    const bool more = (it + 1) < NIT;
    if (more) {
      stage(cur ^ 1, it + 1, xnxt);
      if (it + 2 < NIT) xnxt = *(const float4*)(xbase + (size_t)(it + 2) * 32);
    }
    {
      const char* base = smem + cur * BUF_B;
      const short* xh = (const short*)base;
      const short* xl = (const short*)(base + 2560);
      const char* pt = base + 5120;
      const int kb = (lane >> 4) * 8;
      short8v ah = *(const short8v*)&xh[(16 * wr + lm) * 40 + kb];
      short8v al = *(const short8v*)&xl[(16 * wr + lm) * 40 + kb];
#pragma unroll
      for (int cti = 0; cti < 7; ++cti) {
        if (cti >= nct) continue;
        const int n = (ct0 + cti) * 16 + lm;
        const char* rowp = pt + n * 128;
        const int sw = (n & 7) << 4;
        short8v bh = *(const short8v*)(rowp + (quad ^ sw));
        short8v bl = *(const short8v*)(rowp + ((quad + 64) ^ sw));
        acc[cti] = __builtin_amdgcn_mfma_f32_16x16x32_bf16(ah, bh, acc[cti], 0, 0, 0);
        acc[cti] = __builtin_amdgcn_mfma_f32_16x16x32_bf16(ah, bl, acc[cti], 0, 0, 0);
        acc[cti] = __builtin_amdgcn_mfma_f32_16x16x32_bf16(al, bh, acc[cti], 0, 0, 0);
      }
    }
    __syncthreads();  // drains stage(it+1) vmcnt + protects buf reuse
  }

  // acc -> ps[32][212]; D layout: col=lane&15, row=(lane>>4)*4+rr
#pragma unroll
  for (int cti = 0; cti < 7; ++cti) {
    if (cti >= nct) continue;
    const int col = (ct0 + cti) * 16 + lm;
    const int row0 = 16 * wr + (lane >> 4) * 4;
#pragma unroll
    for (int rr = 0; rr < 4; ++rr)
      ps[(row0 + rr) * 212 + col] = acc[cti][rr];
  }
  __syncthreads();

  for (int idx = t; idx < 32 * 208; idx += 256) {
    const int row = idx / 208, col = idx - row * 208;
    pfeat[((size_t)(r0 + row) * NSLICE + sl) * KP + col] = ps[row * 212 + col];
  }
}

// ---------------------------------------------------------------------------
// Combine partials (fp64, ascending slice order) + fp64 LN + exact rank
// select + mask + flag. Stores masked feat as SWIZZLED bf16 tiles.
// ---------------------------------------------------------------------------
__global__ __launch_bounds__(256) void combine_ln_flag_kernel(
    const float* __restrict__ pfeat,
    const float* __restrict__ lnw, const float* __restrict__ lnb,
    const int* __restrict__ fip, char* __restrict__ featb,
    int* __restrict__ fraglist, int* __restrict__ fragcnt,
    int B, int K) {
  const int t = threadIdx.x;
  const int tx = t & 15, ty = t >> 4;
  const int r0 = blockIdx.x * 32;
  const int need = *fip + 1;
  const unsigned long long INFB = 0xFFFFFFFFFFFFFFFFull;

#pragma unroll
  for (int r = 0; r < 2; ++r) {
    const int rowg = r0 + ty + 16 * r;

    double a[13];
#pragma unroll
    for (int j = 0; j < 13; ++j) {
      const size_t base = (size_t)rowg * NSLICE * KP + tx + 16 * j;
      double v = (double)pfeat[base];
#pragma unroll
      for (int s = 1; s < NSLICE; ++s) v += (double)pfeat[base + (size_t)s * KP];
      a[j] = v;
    }

    double s = 0.0;
#pragma unroll
    for (int j = 0; j < 13; ++j)
      if (tx + 16 * j < K) s += a[j];
    for (int m = 1; m <= 8; m <<= 1) s += __shfl_xor(s, m, 64);
    double mu = s / (double)K;

    double vs = 0.0;
#pragma unroll
    for (int j = 0; j < 13; ++j) {
      if (tx + 16 * j < K) { double d = a[j] - mu; vs = fma(d, d, vs); }
    }
    for (int m = 1; m <= 8; m <<= 1) vs += __shfl_xor(vs, m, 64);
    double rstd = 1.0 / sqrt(vs / (double)K + 1e-5);

    double f[13];
    unsigned long long au[13];
#pragma unroll
    for (int j = 0; j < 13; ++j) {
      int k = tx + 16 * j;
      if (k < K) {
        f[j] = fma((a[j] - mu) * rstd, (double)lnw[k], (double)lnb[k]);
        au[j] = __double_as_longlong(fabs(f[j]));
      } else {
        f[j] = 0.0;
        au[j] = INFB;
      }
    }

    unsigned long long p = 0ull;
    for (int b = 63; b >= 0; --b) {
      unsigned long long tv = p | (1ull << b);
      int cnt = 0;
#pragma unroll
      for (int j = 0; j < 13; ++j) cnt += (au[j] < tv) ? 1 : 0;
      for (int m = 1; m <= 8; m <<= 1) cnt += __shfl_xor(cnt, m, 64);
      if (cnt < need) p = tv;
    }
    unsigned long long mn = INFB;
#pragma unroll
    for (int j = 0; j < 13; ++j)
      if (au[j] > p && au[j] < mn) mn = au[j];
    for (int m = 1; m <= 8; m <<= 1) {
      unsigned long long o = __shfl_xor(mn, m, 64);
      if (o < mn) mn = o;
    }

#pragma unroll
    for (int j = 0; j < 13; ++j) {
      int k = tx + 16 * j;
      if (k < K) {
        float fv = (au[j] > p) ? (float)f[j] : 0.f;
        __hip_bfloat16 hb = __float2bfloat16(fv);
        *(short*)(featb + tb_addr(rowg, k)) = *(short*)&hb;
      }
    }
    for (int k = K + tx; k < 256; k += 16)
      *(short*)(featb + tb_addr(rowg, k)) = 0;

    if (tx == 0) {
      double gap = __longlong_as_double((long long)mn) -
                   __longlong_as_double((long long)p);
      if (gap < GAP_THR) {
        int pos = atomicAdd(fragcnt, 1);
        if (pos < MAXFRAG) fraglist[pos] = rowg;
      }
    }
  }
}

// ---------------------------------------------------------------------------
// Recompute stage 1: fp64 dots of fragile rows. grid (MAXFRAG, 13).
// ---------------------------------------------------------------------------
__global__ __launch_bounds__(256) void recompute_dots_kernel(
    const float* __restrict__ x, const double* __restrict__ pt64k,
    const int* __restrict__ fraglist, const int* __restrict__ fragcnt,
    double* __restrict__ rowdots, int C) {
  int n = *fragcnt; if (n > MAXFRAG) n = MAXFRAG;
  const int bi = blockIdx.x;
  if (bi >= n) return;
  const int r = fraglist[bi];
  const int t = threadIdx.x;
  const int lane = t & 63, w = t >> 6;

  __shared__ float xsh[2048];
  for (int c = t; c < C; c += 256) xsh[c] = x[(size_t)r * C + c];
  __syncthreads();

  const int kbase = blockIdx.y * 16 + w * 4;
  const double* p0 = pt64k + (size_t)(kbase + 0) * C;
  const double* p1 = pt64k + (size_t)(kbase + 1) * C;
  const double* p2 = pt64k + (size_t)(kbase + 2) * C;
  const double* p3 = pt64k + (size_t)(kbase + 3) * C;
  double a0 = 0.0, a1 = 0.0, a2 = 0.0, a3 = 0.0;
#pragma unroll 4
  for (int c = lane; c < C; c += 64) {
    double xc = (double)xsh[c];
    a0 = fma(xc, p0[c], a0);
    a1 = fma(xc, p1[c], a1);
    a2 = fma(xc, p2[c], a2);
    a3 = fma(xc, p3[c], a3);
  }
  for (int m = 1; m <= 32; m <<= 1) {
    a0 += __shfl_xor(a0, m, 64);
    a1 += __shfl_xor(a1, m, 64);
    a2 += __shfl_xor(a2, m, 64);
    a3 += __shfl_xor(a3, m, 64);
  }
  if (lane == 0) {
    rowdots[(size_t)bi * KP + kbase + 0] = a0;
    rowdots[(size_t)bi * KP + kbase + 1] = a1;
    rowdots[(size_t)bi * KP + kbase + 2] = a2;
    rowdots[(size_t)bi * KP + kbase + 3] = a3;
  }
}

// ---------------------------------------------------------------------------
// Recompute stage 2: fp64 LN + exact select + mask -> bf16 featb rewrite.
// ---------------------------------------------------------------------------
__global__ __launch_bounds__(64) void recompute_ln_kernel(
    const double* __restrict__ rowdots,
    const float* __restrict__ lnw, const float* __restrict__ lnb,
    const int* __restrict__ fip, const int* __restrict__ fraglist,
    const int* __restrict__ fragcnt, char* __restrict__ featb,
    unsigned long long* __restrict__ exgap, int* __restrict__ exidx2, int K) {
  int n = *fragcnt; if (n > MAXFRAG) n = MAXFRAG;
  const int bid = blockIdx.x;
  if (bid >= n) return;
  const int r = fraglist[bid];
  const int lane = threadIdx.x;

  const int kk[4] = {lane, lane + 64, lane + 128, lane + 192};
  double aa[4];
#pragma unroll
  for (int j = 0; j < 4; ++j)
    aa[j] = (kk[j] < KP) ? rowdots[(size_t)bid * KP + kk[j]] : 0.0;

  double s = aa[0] + aa[1] + aa[2];
  if (kk[3] < K) s += aa[3];
  for (int m = 1; m <= 32; m <<= 1) s += __shfl_xor(s, m, 64);
  double mu = s / (double)K;

  double vs = 0.0;
#pragma unroll
  for (int j = 0; j < 4; ++j) {
    if (kk[j] < K) { double d = aa[j] - mu; vs = fma(d, d, vs); }
  }
  for (int m = 1; m <= 32; m <<= 1) vs += __shfl_xor(vs, m, 64);
  double rstd = 1.0 / sqrt(vs / (double)K + 1e-5);

  const unsigned long long INFB = 0xFFFFFFFFFFFFFFFFull;
  double f[4]; unsigned long long au[4];
#pragma unroll
  for (int j = 0; j < 4; ++j) {
    if (kk[j] < K) {
      f[j] = fma((aa[j] - mu) * rstd, (double)lnw[kk[j]], (double)lnb[kk[j]]);
      au[j] = __double_as_longlong(fabs(f[j]));
    } else { f[j] = 0.0; au[j] = INFB; }
  }

  const int need = *fip + 1;
  unsigned long long p = 0ull;
  for (int b = 63; b >= 0; --b) {
    unsigned long long tv = p | (1ull << b);
    int cnt = 0;
#pragma unroll
    for (int j = 0; j < 4; ++j)
      cnt += (int)__popcll(__ballot(au[j] < tv));
    if (cnt < need) p = tv;
  }
  unsigned long long mn = INFB;
#pragma unroll
  for (int j = 0; j < 4; ++j)
    if (au[j] > p && au[j] < mn) mn = au[j];
  for (int m = 1; m <= 32; m <<= 1) {
    unsigned long long o = __shfl_xor(mn, m, 64);
    if (o < mn) mn = o;
  }
  int idx2 = -1;
#pragma unroll
  for (int j = 0; j < 4; ++j)
    if (au[j] == mn && kk[j] < K) idx2 = kk[j];
  for (int m = 1; m <= 32; m <<= 1) idx2 = max(idx2, __shfl_xor(idx2, m, 64));

#pragma unroll
  for (int j = 0; j < 4; ++j) {
    if (kk[j] < K) {
      float fv = (au[j] > p) ? (float)f[j] : 0.f;
      __hip_bfloat16 hb = __float2bfloat16(fv);
      *(short*)(featb + tb_addr(r, kk[j])) = *(short*)&hb;
    }
  }
  if (lane == 0) {
    double gap = __longlong_as_double((long long)mn) -
                 __longlong_as_double((long long)p);
    exgap[bid] = (unsigned long long)__double_as_longlong(gap);
    exidx2[bid] = idx2;
  }
}

// ---------------------------------------------------------------------------
// Tie fixup: zero the kept-min element on the global argmin-gap row.
// ---------------------------------------------------------------------------
__global__ void tiefix_kernel(const int* __restrict__ fragcnt,
                              const int* __restrict__ fraglist,
                              const unsigned long long* __restrict__ exgap,
                              const int* __restrict__ exidx2,
                              char* __restrict__ featb, int K) {
  int n = *fragcnt; if (n > MAXFRAG) n = MAXFRAG;
  if (n <= 0) return;
  const int lane = threadIdx.x;
  unsigned long long best = 0xFFFFFFFFFFFFFFFFull; int bi = -1;
  for (int i = lane; i < n; i += 64) {
    unsigned long long g = exgap[i];
    if (g < best) { best = g; bi = i; }
  }
  for (int m = 1; m <= 32; m <<= 1) {
    unsigned long long ob = __shfl_xor(best, m, 64);
    int oi = __shfl_xor(bi, m, 64);
    if (ob < best || (ob == best && oi >= 0 && (bi < 0 || oi < bi))) {
      best = ob; bi = oi;
    }
  }
  if (lane == 0 && bi >= 0) {
    int r = fraglist[bi];
    int idx = exidx2[bi];
    if (idx >= 0 && idx < K) *(short*)(featb + tb_addr(r, idx)) = 0;
  }
}

// ---------------------------------------------------------------------------
// GEMM2 via bf16 MFMA, K-split staging, XCD-swizzled 1D grid (4096 % 8 == 0).
// ---------------------------------------------------------------------------
__global__ __launch_bounds__(256, 5) void gemm2_mfma_kernel(
    const char* __restrict__ featb, const char* __restrict__ fcwb,
    const float* __restrict__ fcb, float* __restrict__ out,
    int B, int NC, int nct) {
  // XCD-aware remap: contiguous chunk per XCD (bijective when total%8==0)
  const int total = gridDim.x;
  const int cpx = total >> 3;
  const int bid = (int)blockIdx.x;
  const int swz = ((total & 7) == 0) ? (bid & 7) * cpx + (bid >> 3) : bid;
  const int by = swz / nct;   // row-tile
  const int bx = swz % nct;   // col-tile

  __shared__ __align__(16) char smem2[32768];
  char* a_s = smem2;
  char* b_s = smem2 + 16384;

  const int t = threadIdx.x;
  const int lane = t & 63;
  const int w = t >> 6;
  const int wr = w & 1, wc = w >> 1;
  const int lm = lane & 15;
  const int qlane = lane >> 4;
  const int r0 = by * 64;
  const int c0 = bx * 64;

  const char* ga = featb + (size_t)by * 32768;
  const char* gb = fcwb + (size_t)bx * 32768;

  f32x4 acc[2][2];
#pragma unroll
  for (int i = 0; i < 2; ++i)
#pragma unroll
    for (int j = 0; j < 2; ++j) acc[i][j] = (f32x4)(0.0f);

  const int ar = 32 * wr + lm, br = 32 * wc + lm;
  const int swa = (ar & 7) << 4, swb = (br & 7) << 4;
  const int lrow = lane >> 4;
  const int lbyt = (lane & 15) * 16;

  for (int kc = 0; kc < 2; ++kc) {
    if (kc) __syncthreads();
#pragma unroll
    for (int j = 0; j < 4; ++j) {
      const int call = w * 4 + j;
      const int row = call * 4 + lrow;
      const size_t goff = (size_t)row * 512 + (size_t)kc * 256 + lbyt;
      __builtin_amdgcn_global_load_lds(
          (const __attribute__((address_space(1))) unsigned int*)(ga + goff),
          (__attribute__((address_space(3))) unsigned int*)(a_s + call * 1024),
          16, 0, 0);
      __builtin_amdgcn_global_load_lds(
          (const __attribute__((address_space(1))) unsigned int*)(gb + goff),
          (__attribute__((address_space(3))) unsigned int*)(b_s + call * 1024),
          16, 0, 0);
    }
    __syncthreads();

    const int nch = kc ? 3 : 4;
#pragma unroll
    for (int ch = 0; ch < 4; ++ch) {
      if (ch >= nch) break;
      const int ql = ch * 4 + qlane;
      short8v ar0 = *(const short8v*)(a_s + ar * 256 + ((ql * 16) ^ swa));
      short8v ar1 = *(const short8v*)(a_s + (ar + 16) * 256 + ((ql * 16) ^ swa));
      short8v br0 = *(const short8v*)(b_s + br * 256 + ((ql * 16) ^ swb));
      short8v br1 = *(const short8v*)(b_s + (br + 16) * 256 + ((ql * 16) ^ swb));
      acc[0][0] = __builtin_amdgcn_mfma_f32_16x16x32_bf16(ar0, br0, acc[0][0], 0, 0, 0);
      acc[0][1] = __builtin_amdgcn_mfma_f32_16x16x32_bf16(ar0, br1, acc[0][1], 0, 0, 0);
      acc[1][0] = __builtin_amdgcn_mfma_f32_16x16x32_bf16(ar1, br0, acc[1][0], 0, 0, 0);
      acc[1][1] = __builtin_amdgcn_mfma_f32_16x16x32_bf16(ar1, br1, acc[1][1], 0, 0, 0);
    }
  }

#pragma unroll
  for (int rt = 0; rt < 2; ++rt) {
    const int row = r0 + 32 * wr + 16 * rt + (lane >> 4) * 4;
#pragma unroll
    for (int ct = 0; ct < 2; ++ct) {
      const int col = c0 + 32 * wc + 16 * ct + lm;
      if (col < NC) {
        const float bb = fcb[col];
#pragma unroll
        for (int r = 0; r < 4; ++r)
          out[(size_t)(row + r) * NC + col] = acc[rt][ct][r] + bb;
      }
    }
  }
}

// ---------------------------------------------------------------------------
extern "C" void kernel_launch(void* const* d_in, const int* in_sizes, int n_in,
                              void* d_out, int out_size, void* d_ws, size_t ws_size,
                              hipStream_t stream) {
  const float* x        = (const float*)d_in[0];
  const float* concepts = (const float*)d_in[1];
  const float* lnw      = (const float*)d_in[2];
  const float* lnb      = (const float*)d_in[3];
  const float* fcw      = (const float*)d_in[4];
  const float* fcb      = (const float*)d_in[5];
  const int*   feat_idx = (const int*)d_in[6];

  const int K  = in_sizes[2];        // 200
  const int C  = in_sizes[1] / K;    // 2048
  const int B  = in_sizes[0] / C;    // 16384
  const int NC = in_sizes[5];        // 1000
  const int NCT = (NC + 63) / 64;    // 16

  char* wsp = (char*)d_ws;
  short* ptile = (short*)wsp;  wsp += (size_t)64 * PT_BYTES;       // 1.7 MB
  double* pt64k = (double*)wsp; wsp += (size_t)KP * C * 8;         // 3.4 MB
  char* featb = wsp;  wsp += (size_t)(B / 64) * 32768;             // 8.4 MB
  char* fcwb = wsp;   wsp += (size_t)NCT * 32768;                  // 512 KB
  int* fragcnt = (int*)wsp;   wsp += 256;
  int* fraglist = (int*)wsp;  wsp += MAXFRAG * 4;
  unsigned long long* exgap = (unsigned long long*)wsp; wsp += MAXFRAG * 8;
  int* exidx2 = (int*)wsp;    wsp += MAXFRAG * 4;
  double* rowdots = (double*)wsp; wsp += (size_t)MAXFRAG * KP * 8;
  float* pfeat = (float*)wsp;  // B * NSLICE * KP * 4 = 27.3 MB

  l2norm_all_kernel<<<KP, 256, 0, stream>>>(concepts, ptile, pt64k, C, K);
  fcw_bf16_kernel<<<NCT * 64, 256, 0, stream>>>(fcw, fcwb, fragcnt, K, NC);
  gemm1_mfma_partial_kernel<<<dim3(B / 32, NSLICE), 256, 0, stream>>>(
      x, ptile, pfeat, B, C, C / NSLICE);
  combine_ln_flag_kernel<<<B / 32, 256, 0, stream>>>(
      pfeat, lnw, lnb, feat_idx, featb, fraglist, fragcnt, B, K);
  recompute_dots_kernel<<<dim3(MAXFRAG, KP / 16), 256, 0, stream>>>(
      x, pt64k, fraglist, fragcnt, rowdots, C);
  recompute_ln_kernel<<<MAXFRAG, 64, 0, stream>>>(
      rowdots, lnw, lnb, feat_idx, fraglist, fragcnt, featb, exgap, exidx2, K);
  tiefix_kernel<<<1, 64, 0, stream>>>(fragcnt, fraglist, exgap, exidx2, featb, K);
  gemm2_mfma_kernel<<<NCT * (B / 64), 256, 0, stream>>>(
      featb, fcwb, fcb, (float*)d_out, B, NC, NCT);
}

// Round 21
// 176.622 us; speedup vs baseline: 1.1470x; 1.1470x over previous
//
#include <hip/hip_runtime.h>
#include <hip/hip_bf16.h>

#define KP   208        // padded K
#define MAXFRAG 256
#define GAP_THR 2e-4
#define NSLICE 2
#define PT_BYTES 26624  // gemm1: per c-tile 208 rows * 128 B (hi|lo swizzled)

typedef __attribute__((ext_vector_type(8))) short short8v;  // 8 bf16
typedef __attribute__((ext_vector_type(4))) float f32x4;

// byte address of element (row, k) in a 64-row x 256-k swizzled bf16 tile set
__device__ __forceinline__ size_t tb_addr(int row, int k) {
  const int tile = row >> 6, r = row & 63, q = k >> 3, e = k & 7;
  return (size_t)tile * 32768 + (size_t)r * 512 +
         (size_t)((((q * 16) ^ ((r & 7) << 4))) + e * 2);
}

// ---------------------------------------------------------------------------
__device__ __forceinline__ double row_norm(const float* v, int C, int tid) {
  double ss = 0.0;
  for (int c = tid; c < C; c += 256) { double t = (double)v[c]; ss = fma(t, t, ss); }
  __shared__ double red[4];
  for (int m = 32; m >= 1; m >>= 1) ss += __shfl_xor(ss, m, 64);
  if ((tid & 63) == 0) red[tid >> 6] = ss;
  __syncthreads();
  double s = red[0] + red[1] + red[2] + red[3];
  double n = sqrt(s);
  return (n < 1e-12) ? 1e-12 : n;
}

// ---------------------------------------------------------------------------
// FUSED l2-normalize: one pass over concepts writes BOTH the swizzled bf16
// hi/lo tiles (gemm1) and the fp64 concept-major proto (recompute path).
// ---------------------------------------------------------------------------
__global__ __launch_bounds__(256) void l2norm_all_kernel(
    const float* __restrict__ concepts, short* __restrict__ ptile,
    double* __restrict__ pt64k, int C, int K) {
  int k = blockIdx.x;  // 0..KP-1
  char* pk = (char*)ptile + (size_t)k * 128;
  if (k >= K) {
    for (int c = threadIdx.x; c < C; c += 256) {
      int ct = c >> 5, cin = c & 31, q = cin >> 3, e = cin & 7;
      char* base = pk + (size_t)ct * PT_BYTES;
      *(short*)(base + (((q * 16) ^ ((k & 7) << 4)) + e * 2)) = 0;
      *(short*)(base + (((q * 16 + 64) ^ ((k & 7) << 4)) + e * 2)) = 0;
      pt64k[(size_t)k * C + c] = 0.0;
    }
    return;
  }
  const float* v = concepts + (size_t)k * C;
  double n = row_norm(v, C, threadIdx.x);
  for (int c = threadIdx.x; c < C; c += 256) {
    double pv = (double)v[c] / n;
    pt64k[(size_t)k * C + c] = pv;
    float f = (float)pv;
    __hip_bfloat16 hb = __float2bfloat16(f);
    float hf = __bfloat162float(hb);
    __hip_bfloat16 lb = __float2bfloat16(f - hf);
    int ct = c >> 5, cin = c & 31, q = cin >> 3, e = cin & 7;
    char* base = pk + (size_t)ct * PT_BYTES;
    *(short*)(base + (((q * 16) ^ ((k & 7) << 4)) + e * 2)) = *(short*)&hb;
    *(short*)(base + (((q * 16 + 64) ^ ((k & 7) << 4)) + e * 2)) = *(short*)&lb;
  }
}

// fcw -> bf16 swizzled tile-major; also zeroes fragcnt (fused zc)
__global__ __launch_bounds__(256) void fcw_bf16_kernel(
    const float* __restrict__ fcw, char* __restrict__ fcwb,
    int* __restrict__ fragcnt, int K, int NC) {
  int idx = blockIdx.x * 256 + threadIdx.x;
  if (idx == 0) *fragcnt = 0;
  int col = idx >> 8, k = idx & 255;
  float v = (col < NC && k < K) ? fcw[(size_t)col * K + k] : 0.f;
  __hip_bfloat16 hb = __float2bfloat16(v);
  *(short*)(fcwb + tb_addr(col, k)) = *(short*)&hb;
}

// ---------------------------------------------------------------------------
// Phase-1 GEMM1 partial: bf16-split MFMA over one C-slice.
// SINGLE-BUFFER, 2 barriers/iter, 4-5 blocks/CU (31.7KB LDS) — proven best
// occupancy/latency tradeoff (r17/r19; double-buffer regressed in r20).
// ---------------------------------------------------------------------------
__global__ __launch_bounds__(256, 5) void gemm1_mfma_partial_kernel(
    const float* __restrict__ x, const short* __restrict__ ptile,
    float* __restrict__ pfeat, int B, int C, int cslice) {
  __shared__ __align__(16) char smem[31744];
  short* xh = (short*)smem;
  short* xl = (short*)(smem + 2560);
  char*  pt = smem + 5120;
  float* ps = (float*)smem;

  const int t = threadIdx.x;
  const int lane = t & 63;
  const int w = t >> 6;
  const int wr = w & 1, wc = w >> 1;
  const int lm = lane & 15;
  const int quad = (lane >> 4) * 16;
  const int r0 = blockIdx.x * 32;
  const int sl = blockIdx.y;
  const int nct = wc ? 6 : 7;
  const int ct0 = wc ? 7 : 0;
  const int ct_base = sl * (cslice >> 5);

  f32x4 acc[7];
#pragma unroll
  for (int j = 0; j < 7; ++j) acc[j] = (f32x4)(0.0f);

  const int xrow = t >> 3, xc4 = (t & 7) * 4;
  const float* xbase = &x[(size_t)(r0 + xrow) * C + sl * cslice + xc4];

  const int c_lo = (w == 0) ? 0 : (w == 1) ? 7 : (w == 2) ? 14 : 20;
  const int c_hi = (w == 0) ? 7 : (w == 1) ? 14 : (w == 2) ? 20 : 26;

  const int NIT = cslice >> 5;
  float4 xreg = *(const float4*)xbase;

  for (int it = 0; it < NIT; ++it) {
    __syncthreads();  // barrier A: prev compute done, LDS free
    {
      const char* gsrc = (const char*)ptile + (size_t)(ct_base + it) * PT_BYTES;
      for (int cc = c_lo; cc < c_hi; ++cc)
        __builtin_amdgcn_global_load_lds(
            (const __attribute__((address_space(1))) unsigned int*)(gsrc + cc * 1024 + lane * 16),
            (__attribute__((address_space(3))) unsigned int*)(pt + cc * 1024),
            16, 0, 0);
      short h[4], l[4];
#pragma unroll
      for (int e = 0; e < 4; ++e) {
        float f = (&xreg.x)[e];
        __hip_bfloat16 hb = __float2bfloat16(f);
        float hf = __bfloat162float(hb);
        __hip_bfloat16 lb = __float2bfloat16(f - hf);
        h[e] = *(short*)&hb;
        l[e] = *(short*)&lb;
      }
      *(short4*)&xh[xrow * 40 + xc4] = make_short4(h[0], h[1], h[2], h[3]);
      *(short4*)&xl[xrow * 40 + xc4] = make_short4(l[0], l[1], l[2], l[3]);
    }
    __syncthreads();  // barrier B: vmcnt(0) drain -> glds + x tile ready
    if (it + 1 < NIT)
      xreg = *(const float4*)(xbase + (size_t)(it + 1) * 32);  // hidden under compute
    {
      const int kb = (lane >> 4) * 8;
      short8v ah = *(const short8v*)&xh[(16 * wr + lm) * 40 + kb];
      short8v al = *(const short8v*)&xl[(16 * wr + lm) * 40 + kb];
#pragma unroll
      for (int cti = 0; cti < 7; ++cti) {
        if (cti >= nct) continue;
        const int n = (ct0 + cti) * 16 + lm;
        const char* rowp = pt + n * 128;
        const int sw = (n & 7) << 4;
        short8v bh = *(const short8v*)(rowp + (quad ^ sw));
        short8v bl = *(const short8v*)(rowp + ((quad + 64) ^ sw));
        acc[cti] = __builtin_amdgcn_mfma_f32_16x16x32_bf16(ah, bh, acc[cti], 0, 0, 0);
        acc[cti] = __builtin_amdgcn_mfma_f32_16x16x32_bf16(ah, bl, acc[cti], 0, 0, 0);
        acc[cti] = __builtin_amdgcn_mfma_f32_16x16x32_bf16(al, bh, acc[cti], 0, 0, 0);
      }
    }
  }
  __syncthreads();

#pragma unroll
  for (int cti = 0; cti < 7; ++cti) {
    if (cti >= nct) continue;
    const int col = (ct0 + cti) * 16 + lm;
    const int row0 = 16 * wr + (lane >> 4) * 4;
#pragma unroll
    for (int rr = 0; rr < 4; ++rr)
      ps[(row0 + rr) * 212 + col] = acc[cti][rr];
  }
  __syncthreads();

  for (int idx = t; idx < 32 * 208; idx += 256) {
    const int row = idx / 208, col = idx - row * 208;
    pfeat[((size_t)(r0 + row) * NSLICE + sl) * KP + col] = ps[row * 212 + col];
  }
}

// ---------------------------------------------------------------------------
// Combine partials (fp64, ascending slice order) + fp64 LN + exact rank
// select + mask + flag. Stores masked feat as SWIZZLED bf16 tiles.
// ---------------------------------------------------------------------------
__global__ __launch_bounds__(256) void combine_ln_flag_kernel(
    const float* __restrict__ pfeat,
    const float* __restrict__ lnw, const float* __restrict__ lnb,
    const int* __restrict__ fip, char* __restrict__ featb,
    int* __restrict__ fraglist, int* __restrict__ fragcnt,
    int B, int K) {
  const int t = threadIdx.x;
  const int tx = t & 15, ty = t >> 4;
  const int r0 = blockIdx.x * 32;
  const int need = *fip + 1;
  const unsigned long long INFB = 0xFFFFFFFFFFFFFFFFull;

#pragma unroll
  for (int r = 0; r < 2; ++r) {
    const int rowg = r0 + ty + 16 * r;

    double a[13];
#pragma unroll
    for (int j = 0; j < 13; ++j) {
      const size_t base = (size_t)rowg * NSLICE * KP + tx + 16 * j;
      double v = (double)pfeat[base];
#pragma unroll
      for (int s = 1; s < NSLICE; ++s) v += (double)pfeat[base + (size_t)s * KP];
      a[j] = v;
    }

    double s = 0.0;
#pragma unroll
    for (int j = 0; j < 13; ++j)
      if (tx + 16 * j < K) s += a[j];
    for (int m = 1; m <= 8; m <<= 1) s += __shfl_xor(s, m, 64);
    double mu = s / (double)K;

    double vs = 0.0;
#pragma unroll
    for (int j = 0; j < 13; ++j) {
      if (tx + 16 * j < K) { double d = a[j] - mu; vs = fma(d, d, vs); }
    }
    for (int m = 1; m <= 8; m <<= 1) vs += __shfl_xor(vs, m, 64);
    double rstd = 1.0 / sqrt(vs / (double)K + 1e-5);

    double f[13];
    unsigned long long au[13];
#pragma unroll
    for (int j = 0; j < 13; ++j) {
      int k = tx + 16 * j;
      if (k < K) {
        f[j] = fma((a[j] - mu) * rstd, (double)lnw[k], (double)lnb[k]);
        au[j] = __double_as_longlong(fabs(f[j]));
      } else {
        f[j] = 0.0;
        au[j] = INFB;
      }
    }

    unsigned long long p = 0ull;
    for (int b = 63; b >= 0; --b) {
      unsigned long long tv = p | (1ull << b);
      int cnt = 0;
#pragma unroll
      for (int j = 0; j < 13; ++j) cnt += (au[j] < tv) ? 1 : 0;
      for (int m = 1; m <= 8; m <<= 1) cnt += __shfl_xor(cnt, m, 64);
      if (cnt < need) p = tv;
    }
    unsigned long long mn = INFB;
#pragma unroll
    for (int j = 0; j < 13; ++j)
      if (au[j] > p && au[j] < mn) mn = au[j];
    for (int m = 1; m <= 8; m <<= 1) {
      unsigned long long o = __shfl_xor(mn, m, 64);
      if (o < mn) mn = o;
    }

#pragma unroll
    for (int j = 0; j < 13; ++j) {
      int k = tx + 16 * j;
      if (k < K) {
        float fv = (au[j] > p) ? (float)f[j] : 0.f;
        __hip_bfloat16 hb = __float2bfloat16(fv);
        *(short*)(featb + tb_addr(rowg, k)) = *(short*)&hb;
      }
    }
    for (int k = K + tx; k < 256; k += 16)
      *(short*)(featb + tb_addr(rowg, k)) = 0;

    if (tx == 0) {
      double gap = __longlong_as_double((long long)mn) -
                   __longlong_as_double((long long)p);
      if (gap < GAP_THR) {
        int pos = atomicAdd(fragcnt, 1);
        if (pos < MAXFRAG) fraglist[pos] = rowg;
      }
    }
  }
}

// ---------------------------------------------------------------------------
// Recompute stage 1: fp64 dots of fragile rows. grid (MAXFRAG, 13).
// ---------------------------------------------------------------------------
__global__ __launch_bounds__(256) void recompute_dots_kernel(
    const float* __restrict__ x, const double* __restrict__ pt64k,
    const int* __restrict__ fraglist, const int* __restrict__ fragcnt,
    double* __restrict__ rowdots, int C) {
  int n = *fragcnt; if (n > MAXFRAG) n = MAXFRAG;
  const int bi = blockIdx.x;
  if (bi >= n) return;
  const int r = fraglist[bi];
  const int t = threadIdx.x;
  const int lane = t & 63, w = t >> 6;

  __shared__ float xsh[2048];
  for (int c = t; c < C; c += 256) xsh[c] = x[(size_t)r * C + c];
  __syncthreads();

  const int kbase = blockIdx.y * 16 + w * 4;
  const double* p0 = pt64k + (size_t)(kbase + 0) * C;
  const double* p1 = pt64k + (size_t)(kbase + 1) * C;
  const double* p2 = pt64k + (size_t)(kbase + 2) * C;
  const double* p3 = pt64k + (size_t)(kbase + 3) * C;
  double a0 = 0.0, a1 = 0.0, a2 = 0.0, a3 = 0.0;
#pragma unroll 4
  for (int c = lane; c < C; c += 64) {
    double xc = (double)xsh[c];
    a0 = fma(xc, p0[c], a0);
    a1 = fma(xc, p1[c], a1);
    a2 = fma(xc, p2[c], a2);
    a3 = fma(xc, p3[c], a3);
  }
  for (int m = 1; m <= 32; m <<= 1) {
    a0 += __shfl_xor(a0, m, 64);
    a1 += __shfl_xor(a1, m, 64);
    a2 += __shfl_xor(a2, m, 64);
    a3 += __shfl_xor(a3, m, 64);
  }
  if (lane == 0) {
    rowdots[(size_t)bi * KP + kbase + 0] = a0;
    rowdots[(size_t)bi * KP + kbase + 1] = a1;
    rowdots[(size_t)bi * KP + kbase + 2] = a2;
    rowdots[(size_t)bi * KP + kbase + 3] = a3;
  }
}

// ---------------------------------------------------------------------------
// Recompute stage 2: fp64 LN + exact select + mask -> bf16 featb rewrite.
// ---------------------------------------------------------------------------
__global__ __launch_bounds__(64) void recompute_ln_kernel(
    const double* __restrict__ rowdots,
    const float* __restrict__ lnw, const float* __restrict__ lnb,
    const int* __restrict__ fip, const int* __restrict__ fraglist,
    const int* __restrict__ fragcnt, char* __restrict__ featb,
    unsigned long long* __restrict__ exgap, int* __restrict__ exidx2, int K) {
  int n = *fragcnt; if (n > MAXFRAG) n = MAXFRAG;
  const int bid = blockIdx.x;
  if (bid >= n) return;
  const int r = fraglist[bid];
  const int lane = threadIdx.x;

  const int kk[4] = {lane, lane + 64, lane + 128, lane + 192};
  double aa[4];
#pragma unroll
  for (int j = 0; j < 4; ++j)
    aa[j] = (kk[j] < KP) ? rowdots[(size_t)bid * KP + kk[j]] : 0.0;

  double s = aa[0] + aa[1] + aa[2];
  if (kk[3] < K) s += aa[3];
  for (int m = 1; m <= 32; m <<= 1) s += __shfl_xor(s, m, 64);
  double mu = s / (double)K;

  double vs = 0.0;
#pragma unroll
  for (int j = 0; j < 4; ++j) {
    if (kk[j] < K) { double d = aa[j] - mu; vs = fma(d, d, vs); }
  }
  for (int m = 1; m <= 32; m <<= 1) vs += __shfl_xor(vs, m, 64);
  double rstd = 1.0 / sqrt(vs / (double)K + 1e-5);

  const unsigned long long INFB = 0xFFFFFFFFFFFFFFFFull;
  double f[4]; unsigned long long au[4];
#pragma unroll
  for (int j = 0; j < 4; ++j) {
    if (kk[j] < K) {
      f[j] = fma((aa[j] - mu) * rstd, (double)lnw[kk[j]], (double)lnb[kk[j]]);
      au[j] = __double_as_longlong(fabs(f[j]));
    } else { f[j] = 0.0; au[j] = INFB; }
  }

  const int need = *fip + 1;
  unsigned long long p = 0ull;
  for (int b = 63; b >= 0; --b) {
    unsigned long long tv = p | (1ull << b);
    int cnt = 0;
#pragma unroll
    for (int j = 0; j < 4; ++j)
      cnt += (int)__popcll(__ballot(au[j] < tv));
    if (cnt < need) p = tv;
  }
  unsigned long long mn = INFB;
#pragma unroll
  for (int j = 0; j < 4; ++j)
    if (au[j] > p && au[j] < mn) mn = au[j];
  for (int m = 1; m <= 32; m <<= 1) {
    unsigned long long o = __shfl_xor(mn, m, 64);
    if (o < mn) mn = o;
  }
  int idx2 = -1;
#pragma unroll
  for (int j = 0; j < 4; ++j)
    if (au[j] == mn && kk[j] < K) idx2 = kk[j];
  for (int m = 1; m <= 32; m <<= 1) idx2 = max(idx2, __shfl_xor(idx2, m, 64));

#pragma unroll
  for (int j = 0; j < 4; ++j) {
    if (kk[j] < K) {
      float fv = (au[j] > p) ? (float)f[j] : 0.f;
      __hip_bfloat16 hb = __float2bfloat16(fv);
      *(short*)(featb + tb_addr(r, kk[j])) = *(short*)&hb;
    }
  }
  if (lane == 0) {
    double gap = __longlong_as_double((long long)mn) -
                 __longlong_as_double((long long)p);
    exgap[bid] = (unsigned long long)__double_as_longlong(gap);
    exidx2[bid] = idx2;
  }
}

// ---------------------------------------------------------------------------
// Tie fixup: zero the kept-min element on the global argmin-gap row.
// ---------------------------------------------------------------------------
__global__ void tiefix_kernel(const int* __restrict__ fragcnt,
                              const int* __restrict__ fraglist,
                              const unsigned long long* __restrict__ exgap,
                              const int* __restrict__ exidx2,
                              char* __restrict__ featb, int K) {
  int n = *fragcnt; if (n > MAXFRAG) n = MAXFRAG;
  if (n <= 0) return;
  const int lane = threadIdx.x;
  unsigned long long best = 0xFFFFFFFFFFFFFFFFull; int bi = -1;
  for (int i = lane; i < n; i += 64) {
    unsigned long long g = exgap[i];
    if (g < best) { best = g; bi = i; }
  }
  for (int m = 1; m <= 32; m <<= 1) {
    unsigned long long ob = __shfl_xor(best, m, 64);
    int oi = __shfl_xor(bi, m, 64);
    if (ob < best || (ob == best && oi >= 0 && (bi < 0 || oi < bi))) {
      best = ob; bi = oi;
    }
  }
  if (lane == 0 && bi >= 0) {
    int r = fraglist[bi];
    int idx = exidx2[bi];
    if (idx >= 0 && idx < K) *(short*)(featb + tb_addr(r, idx)) = 0;
  }
}

// ---------------------------------------------------------------------------
// GEMM2 via bf16 MFMA, K-split staging, XCD-swizzled 1D grid (4096 % 8 == 0).
// ---------------------------------------------------------------------------
__global__ __launch_bounds__(256, 5) void gemm2_mfma_kernel(
    const char* __restrict__ featb, const char* __restrict__ fcwb,
    const float* __restrict__ fcb, float* __restrict__ out,
    int B, int NC, int nct) {
  const int total = gridDim.x;
  const int cpx = total >> 3;
  const int bid = (int)blockIdx.x;
  const int swz = ((total & 7) == 0) ? (bid & 7) * cpx + (bid >> 3) : bid;
  const int by = swz / nct;
  const int bx = swz % nct;

  __shared__ __align__(16) char smem2[32768];
  char* a_s = smem2;
  char* b_s = smem2 + 16384;

  const int t = threadIdx.x;
  const int lane = t & 63;
  const int w = t >> 6;
  const int wr = w & 1, wc = w >> 1;
  const int lm = lane & 15;
  const int qlane = lane >> 4;
  const int r0 = by * 64;
  const int c0 = bx * 64;

  const char* ga = featb + (size_t)by * 32768;
  const char* gb = fcwb + (size_t)bx * 32768;

  f32x4 acc[2][2];
#pragma unroll
  for (int i = 0; i < 2; ++i)
#pragma unroll
    for (int j = 0; j < 2; ++j) acc[i][j] = (f32x4)(0.0f);

  const int ar = 32 * wr + lm, br = 32 * wc + lm;
  const int swa = (ar & 7) << 4, swb = (br & 7) << 4;
  const int lrow = lane >> 4;
  const int lbyt = (lane & 15) * 16;

  for (int kc = 0; kc < 2; ++kc) {
    if (kc) __syncthreads();
#pragma unroll
    for (int j = 0; j < 4; ++j) {
      const int call = w * 4 + j;
      const int row = call * 4 + lrow;
      const size_t goff = (size_t)row * 512 + (size_t)kc * 256 + lbyt;
      __builtin_amdgcn_global_load_lds(
          (const __attribute__((address_space(1))) unsigned int*)(ga + goff),
          (__attribute__((address_space(3))) unsigned int*)(a_s + call * 1024),
          16, 0, 0);
      __builtin_amdgcn_global_load_lds(
          (const __attribute__((address_space(1))) unsigned int*)(gb + goff),
          (__attribute__((address_space(3))) unsigned int*)(b_s + call * 1024),
          16, 0, 0);
    }
    __syncthreads();

    const int nch = kc ? 3 : 4;
#pragma unroll
    for (int ch = 0; ch < 4; ++ch) {
      if (ch >= nch) break;
      const int ql = ch * 4 + qlane;
      short8v ar0 = *(const short8v*)(a_s + ar * 256 + ((ql * 16) ^ swa));
      short8v ar1 = *(const short8v*)(a_s + (ar + 16) * 256 + ((ql * 16) ^ swa));
      short8v br0 = *(const short8v*)(b_s + br * 256 + ((ql * 16) ^ swb));
      short8v br1 = *(const short8v*)(b_s + (br + 16) * 256 + ((ql * 16) ^ swb));
      acc[0][0] = __builtin_amdgcn_mfma_f32_16x16x32_bf16(ar0, br0, acc[0][0], 0, 0, 0);
      acc[0][1] = __builtin_amdgcn_mfma_f32_16x16x32_bf16(ar0, br1, acc[0][1], 0, 0, 0);
      acc[1][0] = __builtin_amdgcn_mfma_f32_16x16x32_bf16(ar1, br0, acc[1][0], 0, 0, 0);
      acc[1][1] = __builtin_amdgcn_mfma_f32_16x16x32_bf16(ar1, br1, acc[1][1], 0, 0, 0);
    }
  }

#pragma unroll
  for (int rt = 0; rt < 2; ++rt) {
    const int row = r0 + 32 * wr + 16 * rt + (lane >> 4) * 4;
#pragma unroll
    for (int ct = 0; ct < 2; ++ct) {
      const int col = c0 + 32 * wc + 16 * ct + lm;
      if (col < NC) {
        const float bb = fcb[col];
#pragma unroll
        for (int r = 0; r < 4; ++r)
          out[(size_t)(row + r) * NC + col] = acc[rt][ct][r] + bb;
      }
    }
  }
}

// ---------------------------------------------------------------------------
extern "C" void kernel_launch(void* const* d_in, const int* in_sizes, int n_in,
                              void* d_out, int out_size, void* d_ws, size_t ws_size,
                              hipStream_t stream) {
  const float* x        = (const float*)d_in[0];
  const float* concepts = (const float*)d_in[1];
  const float* lnw      = (const float*)d_in[2];
  const float* lnb      = (const float*)d_in[3];
  const float* fcw      = (const float*)d_in[4];
  const float* fcb      = (const float*)d_in[5];
  const int*   feat_idx = (const int*)d_in[6];

  const int K  = in_sizes[2];        // 200
  const int C  = in_sizes[1] / K;    // 2048
  const int B  = in_sizes[0] / C;    // 16384
  const int NC = in_sizes[5];        // 1000
  const int NCT = (NC + 63) / 64;    // 16

  char* wsp = (char*)d_ws;
  short* ptile = (short*)wsp;  wsp += (size_t)64 * PT_BYTES;       // 1.7 MB
  double* pt64k = (double*)wsp; wsp += (size_t)KP * C * 8;         // 3.4 MB
  char* featb = wsp;  wsp += (size_t)(B / 64) * 32768;             // 8.4 MB
  char* fcwb = wsp;   wsp += (size_t)NCT * 32768;                  // 512 KB
  int* fragcnt = (int*)wsp;   wsp += 256;
  int* fraglist = (int*)wsp;  wsp += MAXFRAG * 4;
  unsigned long long* exgap = (unsigned long long*)wsp; wsp += MAXFRAG * 8;
  int* exidx2 = (int*)wsp;    wsp += MAXFRAG * 4;
  double* rowdots = (double*)wsp; wsp += (size_t)MAXFRAG * KP * 8;
  float* pfeat = (float*)wsp;  // B * NSLICE * KP * 4 = 27.3 MB

  l2norm_all_kernel<<<KP, 256, 0, stream>>>(concepts, ptile, pt64k, C, K);
  fcw_bf16_kernel<<<NCT * 64, 256, 0, stream>>>(fcw, fcwb, fragcnt, K, NC);
  gemm1_mfma_partial_kernel<<<dim3(B / 32, NSLICE), 256, 0, stream>>>(
      x, ptile, pfeat, B, C, C / NSLICE);
  combine_ln_flag_kernel<<<B / 32, 256, 0, stream>>>(
      pfeat, lnw, lnb, feat_idx, featb, fraglist, fragcnt, B, K);
  recompute_dots_kernel<<<dim3(MAXFRAG, KP / 16), 256, 0, stream>>>(
      x, pt64k, fraglist, fragcnt, rowdots, C);
  recompute_ln_kernel<<<MAXFRAG, 64, 0, stream>>>(
      rowdots, lnw, lnb, feat_idx, fraglist, fragcnt, featb, exgap, exidx2, K);
  tiefix_kernel<<<1, 64, 0, stream>>>(fragcnt, fraglist, exgap, exidx2, featb, K);
  gemm2_mfma_kernel<<<NCT * (B / 64), 256, 0, stream>>>(
      featb, fcwb, fcb, (float*)d_out, B, NC, NCT);
}

// Round 22
// 161.826 us; speedup vs baseline: 1.2519x; 1.0914x over previous
//
#include <hip/hip_runtime.h>
#include <hip/hip_bf16.h>

#define KP   208        // padded K
#define MAXFRAG 256
#define GAP_THR 2e-4f
#define NSLICE 2
#define PT_BYTES 26624  // gemm1: per c-tile 208 rows * 128 B (hi|lo swizzled)

typedef __attribute__((ext_vector_type(8))) short short8v;  // 8 bf16
typedef __attribute__((ext_vector_type(4))) float f32x4;

// byte address of element (row, k) in a 64-row x 256-k swizzled bf16 tile set
__device__ __forceinline__ size_t tb_addr(int row, int k) {
  const int tile = row >> 6, r = row & 63, q = k >> 3, e = k & 7;
  return (size_t)tile * 32768 + (size_t)r * 512 +
         (size_t)((((q * 16) ^ ((r & 7) << 4))) + e * 2);
}

// ---------------------------------------------------------------------------
__device__ __forceinline__ double row_norm(const float* v, int C, int tid) {
  double ss = 0.0;
  for (int c = tid; c < C; c += 256) { double t = (double)v[c]; ss = fma(t, t, ss); }
  __shared__ double red[4];
  for (int m = 32; m >= 1; m >>= 1) ss += __shfl_xor(ss, m, 64);
  if ((tid & 63) == 0) red[tid >> 6] = ss;
  __syncthreads();
  double s = red[0] + red[1] + red[2] + red[3];
  double n = sqrt(s);
  return (n < 1e-12) ? 1e-12 : n;
}

// ---------------------------------------------------------------------------
// FUSED l2-normalize, 4-way parallel over C-quarters: each block computes the
// full-row norm (deterministic identical reduction) and writes its quarter
// of the swizzled bf16 tiles + fp64 concept-major proto.
// ---------------------------------------------------------------------------
__global__ __launch_bounds__(256) void l2norm_all_kernel(
    const float* __restrict__ concepts, short* __restrict__ ptile,
    double* __restrict__ pt64k, int C, int K) {
  int k = blockIdx.x;  // 0..KP-1
  const int qtr = blockIdx.y;
  const int cq = C >> 2;
  const int cbeg = qtr * cq, cend = cbeg + cq;
  char* pk = (char*)ptile + (size_t)k * 128;
  if (k >= K) {
    for (int c = cbeg + (int)threadIdx.x; c < cend; c += 256) {
      int ct = c >> 5, cin = c & 31, q = cin >> 3, e = cin & 7;
      char* base = pk + (size_t)ct * PT_BYTES;
      *(short*)(base + (((q * 16) ^ ((k & 7) << 4)) + e * 2)) = 0;
      *(short*)(base + (((q * 16 + 64) ^ ((k & 7) << 4)) + e * 2)) = 0;
      pt64k[(size_t)k * C + c] = 0.0;
    }
    return;
  }
  const float* v = concepts + (size_t)k * C;
  double n = row_norm(v, C, threadIdx.x);
  for (int c = cbeg + (int)threadIdx.x; c < cend; c += 256) {
    double pv = (double)v[c] / n;
    pt64k[(size_t)k * C + c] = pv;
    float f = (float)pv;
    __hip_bfloat16 hb = __float2bfloat16(f);
    float hf = __bfloat162float(hb);
    __hip_bfloat16 lb = __float2bfloat16(f - hf);
    int ct = c >> 5, cin = c & 31, q = cin >> 3, e = cin & 7;
    char* base = pk + (size_t)ct * PT_BYTES;
    *(short*)(base + (((q * 16) ^ ((k & 7) << 4)) + e * 2)) = *(short*)&hb;
    *(short*)(base + (((q * 16 + 64) ^ ((k & 7) << 4)) + e * 2)) = *(short*)&lb;
  }
}

// fcw -> bf16 swizzled tile-major; also zeroes fragcnt (fused zc)
__global__ __launch_bounds__(256) void fcw_bf16_kernel(
    const float* __restrict__ fcw, char* __restrict__ fcwb,
    int* __restrict__ fragcnt, int K, int NC) {
  int idx = blockIdx.x * 256 + threadIdx.x;
  if (idx == 0) *fragcnt = 0;
  int col = idx >> 8, k = idx & 255;
  float v = (col < NC && k < K) ? fcw[(size_t)col * K + k] : 0.f;
  __hip_bfloat16 hb = __float2bfloat16(v);
  *(short*)(fcwb + tb_addr(col, k)) = *(short*)&hb;
}

// ---------------------------------------------------------------------------
// Phase-1 GEMM1 partial: bf16-split MFMA over one C-slice.
// SINGLE-BUFFER, 2 barriers/iter, 4-5 blocks/CU (31.7KB LDS) — proven best
// occupancy/latency tradeoff (r17/r19/r21; double-buffer regressed r20).
// ---------------------------------------------------------------------------
__global__ __launch_bounds__(256, 5) void gemm1_mfma_partial_kernel(
    const float* __restrict__ x, const short* __restrict__ ptile,
    float* __restrict__ pfeat, int B, int C, int cslice) {
  __shared__ __align__(16) char smem[31744];
  short* xh = (short*)smem;
  short* xl = (short*)(smem + 2560);
  char*  pt = smem + 5120;
  float* ps = (float*)smem;

  const int t = threadIdx.x;
  const int lane = t & 63;
  const int w = t >> 6;
  const int wr = w & 1, wc = w >> 1;
  const int lm = lane & 15;
  const int quad = (lane >> 4) * 16;
  const int r0 = blockIdx.x * 32;
  const int sl = blockIdx.y;
  const int nct = wc ? 6 : 7;
  const int ct0 = wc ? 7 : 0;
  const int ct_base = sl * (cslice >> 5);

  f32x4 acc[7];
#pragma unroll
  for (int j = 0; j < 7; ++j) acc[j] = (f32x4)(0.0f);

  const int xrow = t >> 3, xc4 = (t & 7) * 4;
  const float* xbase = &x[(size_t)(r0 + xrow) * C + sl * cslice + xc4];

  const int c_lo = (w == 0) ? 0 : (w == 1) ? 7 : (w == 2) ? 14 : 20;
  const int c_hi = (w == 0) ? 7 : (w == 1) ? 14 : (w == 2) ? 20 : 26;

  const int NIT = cslice >> 5;
  float4 xreg = *(const float4*)xbase;

  for (int it = 0; it < NIT; ++it) {
    __syncthreads();  // barrier A: prev compute done, LDS free
    {
      const char* gsrc = (const char*)ptile + (size_t)(ct_base + it) * PT_BYTES;
      for (int cc = c_lo; cc < c_hi; ++cc)
        __builtin_amdgcn_global_load_lds(
            (const __attribute__((address_space(1))) unsigned int*)(gsrc + cc * 1024 + lane * 16),
            (__attribute__((address_space(3))) unsigned int*)(pt + cc * 1024),
            16, 0, 0);
      short h[4], l[4];
#pragma unroll
      for (int e = 0; e < 4; ++e) {
        float f = (&xreg.x)[e];
        __hip_bfloat16 hb = __float2bfloat16(f);
        float hf = __bfloat162float(hb);
        __hip_bfloat16 lb = __float2bfloat16(f - hf);
        h[e] = *(short*)&hb;
        l[e] = *(short*)&lb;
      }
      *(short4*)&xh[xrow * 40 + xc4] = make_short4(h[0], h[1], h[2], h[3]);
      *(short4*)&xl[xrow * 40 + xc4] = make_short4(l[0], l[1], l[2], l[3]);
    }
    __syncthreads();  // barrier B: vmcnt(0) drain -> glds + x tile ready
    if (it + 1 < NIT)
      xreg = *(const float4*)(xbase + (size_t)(it + 1) * 32);  // hidden under compute
    {
      const int kb = (lane >> 4) * 8;
      short8v ah = *(const short8v*)&xh[(16 * wr + lm) * 40 + kb];
      short8v al = *(const short8v*)&xl[(16 * wr + lm) * 40 + kb];
#pragma unroll
      for (int cti = 0; cti < 7; ++cti) {
        if (cti >= nct) continue;
        const int n = (ct0 + cti) * 16 + lm;
        const char* rowp = pt + n * 128;
        const int sw = (n & 7) << 4;
        short8v bh = *(const short8v*)(rowp + (quad ^ sw));
        short8v bl = *(const short8v*)(rowp + ((quad + 64) ^ sw));
        acc[cti] = __builtin_amdgcn_mfma_f32_16x16x32_bf16(ah, bh, acc[cti], 0, 0, 0);
        acc[cti] = __builtin_amdgcn_mfma_f32_16x16x32_bf16(ah, bl, acc[cti], 0, 0, 0);
        acc[cti] = __builtin_amdgcn_mfma_f32_16x16x32_bf16(al, bh, acc[cti], 0, 0, 0);
      }
    }
  }
  __syncthreads();

#pragma unroll
  for (int cti = 0; cti < 7; ++cti) {
    if (cti >= nct) continue;
    const int col = (ct0 + cti) * 16 + lm;
    const int row0 = 16 * wr + (lane >> 4) * 4;
#pragma unroll
    for (int rr = 0; rr < 4; ++rr)
      ps[(row0 + rr) * 212 + col] = acc[cti][rr];
  }
  __syncthreads();

  for (int idx = t; idx < 32 * 208; idx += 256) {
    const int row = idx / 208, col = idx - row * 208;
    pfeat[((size_t)(r0 + row) * NSLICE + sl) * KP + col] = ps[row * 212 + col];
  }
}

// ---------------------------------------------------------------------------
// Combine partials (fp64, ascending slice order) + fp64 LN; rank selection in
// FP32 bit-space (32-step bit-descend; monotone rounding => decisions match
// fp64 for all rows with gap > fp32-ulp; smaller-gap rows are flagged and
// exactly recomputed). Stores masked feat as SWIZZLED bf16 tiles.
// ---------------------------------------------------------------------------
__global__ __launch_bounds__(256) void combine_ln_flag_kernel(
    const float* __restrict__ pfeat,
    const float* __restrict__ lnw, const float* __restrict__ lnb,
    const int* __restrict__ fip, char* __restrict__ featb,
    int* __restrict__ fraglist, int* __restrict__ fragcnt,
    int B, int K) {
  const int t = threadIdx.x;
  const int tx = t & 15, ty = t >> 4;
  const int r0 = blockIdx.x * 32;
  const int need = *fip + 1;
  const unsigned INFB32 = 0xFFFFFFFFu;

#pragma unroll
  for (int r = 0; r < 2; ++r) {
    const int rowg = r0 + ty + 16 * r;

    double a[13];
#pragma unroll
    for (int j = 0; j < 13; ++j) {
      const size_t base = (size_t)rowg * NSLICE * KP + tx + 16 * j;
      double v = (double)pfeat[base];
#pragma unroll
      for (int s = 1; s < NSLICE; ++s) v += (double)pfeat[base + (size_t)s * KP];
      a[j] = v;
    }

    double s = 0.0;
#pragma unroll
    for (int j = 0; j < 13; ++j)
      if (tx + 16 * j < K) s += a[j];
    for (int m = 1; m <= 8; m <<= 1) s += __shfl_xor(s, m, 64);
    double mu = s / (double)K;

    double vs = 0.0;
#pragma unroll
    for (int j = 0; j < 13; ++j) {
      if (tx + 16 * j < K) { double d = a[j] - mu; vs = fma(d, d, vs); }
    }
    for (int m = 1; m <= 8; m <<= 1) vs += __shfl_xor(vs, m, 64);
    double rstd = 1.0 / sqrt(vs / (double)K + 1e-5);

    float fl[13];
    unsigned au[13];
#pragma unroll
    for (int j = 0; j < 13; ++j) {
      int k = tx + 16 * j;
      if (k < K) {
        fl[j] = (float)fma((a[j] - mu) * rstd, (double)lnw[k], (double)lnb[k]);
        au[j] = __float_as_uint(fabsf(fl[j]));
      } else {
        fl[j] = 0.f;
        au[j] = INFB32;
      }
    }

    // p = rank-need smallest fp32 |f| bit pattern (32-step bit-descend)
    unsigned p = 0u;
    for (int b = 31; b >= 0; --b) {
      unsigned tv = p | (1u << b);
      int cnt = 0;
#pragma unroll
      for (int j = 0; j < 13; ++j) cnt += (au[j] < tv) ? 1 : 0;
      for (int m = 1; m <= 8; m <<= 1) cnt += __shfl_xor(cnt, m, 64);
      if (cnt < need) p = tv;
    }
    // mn = smallest pattern strictly greater than p (kept-set min)
    unsigned mn = INFB32;
#pragma unroll
    for (int j = 0; j < 13; ++j)
      if (au[j] > p && au[j] < mn) mn = au[j];
    for (int m = 1; m <= 8; m <<= 1) {
      unsigned o = __shfl_xor(mn, m, 64);
      if (o < mn) mn = o;
    }

#pragma unroll
    for (int j = 0; j < 13; ++j) {
      int k = tx + 16 * j;
      if (k < K) {
        float fv = (au[j] > p) ? fl[j] : 0.f;
        __hip_bfloat16 hb = __float2bfloat16(fv);
        *(short*)(featb + tb_addr(rowg, k)) = *(short*)&hb;
      }
    }
    for (int k = K + tx; k < 256; k += 16)
      *(short*)(featb + tb_addr(rowg, k)) = 0;

    if (tx == 0) {
      float gap = __uint_as_float(mn) - __uint_as_float(p);
      if (gap < GAP_THR) {
        int pos = atomicAdd(fragcnt, 1);
        if (pos < MAXFRAG) fraglist[pos] = rowg;
      }
    }
  }
}

// ---------------------------------------------------------------------------
// Recompute stage 1: fp64 dots of fragile rows. grid (MAXFRAG, 13).
// ---------------------------------------------------------------------------
__global__ __launch_bounds__(256) void recompute_dots_kernel(
    const float* __restrict__ x, const double* __restrict__ pt64k,
    const int* __restrict__ fraglist, const int* __restrict__ fragcnt,
    double* __restrict__ rowdots, int C) {
  int n = *fragcnt; if (n > MAXFRAG) n = MAXFRAG;
  const int bi = blockIdx.x;
  if (bi >= n) return;
  const int r = fraglist[bi];
  const int t = threadIdx.x;
  const int lane = t & 63, w = t >> 6;

  __shared__ float xsh[2048];
  for (int c = t; c < C; c += 256) xsh[c] = x[(size_t)r * C + c];
  __syncthreads();

  const int kbase = blockIdx.y * 16 + w * 4;
  const double* p0 = pt64k + (size_t)(kbase + 0) * C;
  const double* p1 = pt64k + (size_t)(kbase + 1) * C;
  const double* p2 = pt64k + (size_t)(kbase + 2) * C;
  const double* p3 = pt64k + (size_t)(kbase + 3) * C;
  double a0 = 0.0, a1 = 0.0, a2 = 0.0, a3 = 0.0;
#pragma unroll 4
  for (int c = lane; c < C; c += 64) {
    double xc = (double)xsh[c];
    a0 = fma(xc, p0[c], a0);
    a1 = fma(xc, p1[c], a1);
    a2 = fma(xc, p2[c], a2);
    a3 = fma(xc, p3[c], a3);
  }
  for (int m = 1; m <= 32; m <<= 1) {
    a0 += __shfl_xor(a0, m, 64);
    a1 += __shfl_xor(a1, m, 64);
    a2 += __shfl_xor(a2, m, 64);
    a3 += __shfl_xor(a3, m, 64);
  }
  if (lane == 0) {
    rowdots[(size_t)bi * KP + kbase + 0] = a0;
    rowdots[(size_t)bi * KP + kbase + 1] = a1;
    rowdots[(size_t)bi * KP + kbase + 2] = a2;
    rowdots[(size_t)bi * KP + kbase + 3] = a3;
  }
}

// ---------------------------------------------------------------------------
// Recompute stage 2: fp64 LN + exact select + mask -> bf16 featb rewrite.
// ---------------------------------------------------------------------------
__global__ __launch_bounds__(64) void recompute_ln_kernel(
    const double* __restrict__ rowdots,
    const float* __restrict__ lnw, const float* __restrict__ lnb,
    const int* __restrict__ fip, const int* __restrict__ fraglist,
    const int* __restrict__ fragcnt, char* __restrict__ featb,
    unsigned long long* __restrict__ exgap, int* __restrict__ exidx2, int K) {
  int n = *fragcnt; if (n > MAXFRAG) n = MAXFRAG;
  const int bid = blockIdx.x;
  if (bid >= n) return;
  const int r = fraglist[bid];
  const int lane = threadIdx.x;

  const int kk[4] = {lane, lane + 64, lane + 128, lane + 192};
  double aa[4];
#pragma unroll
  for (int j = 0; j < 4; ++j)
    aa[j] = (kk[j] < KP) ? rowdots[(size_t)bid * KP + kk[j]] : 0.0;

  double s = aa[0] + aa[1] + aa[2];
  if (kk[3] < K) s += aa[3];
  for (int m = 1; m <= 32; m <<= 1) s += __shfl_xor(s, m, 64);
  double mu = s / (double)K;

  double vs = 0.0;
#pragma unroll
  for (int j = 0; j < 4; ++j) {
    if (kk[j] < K) { double d = aa[j] - mu; vs = fma(d, d, vs); }
  }
  for (int m = 1; m <= 32; m <<= 1) vs += __shfl_xor(vs, m, 64);
  double rstd = 1.0 / sqrt(vs / (double)K + 1e-5);

  const unsigned long long INFB = 0xFFFFFFFFFFFFFFFFull;
  double f[4]; unsigned long long au[4];
#pragma unroll
  for (int j = 0; j < 4; ++j) {
    if (kk[j] < K) {
      f[j] = fma((aa[j] - mu) * rstd, (double)lnw[kk[j]], (double)lnb[kk[j]]);
      au[j] = __double_as_longlong(fabs(f[j]));
    } else { f[j] = 0.0; au[j] = INFB; }
  }

  const int need = *fip + 1;
  unsigned long long p = 0ull;
  for (int b = 63; b >= 0; --b) {
    unsigned long long tv = p | (1ull << b);
    int cnt = 0;
#pragma unroll
    for (int j = 0; j < 4; ++j)
      cnt += (int)__popcll(__ballot(au[j] < tv));
    if (cnt < need) p = tv;
  }
  unsigned long long mn = INFB;
#pragma unroll
  for (int j = 0; j < 4; ++j)
    if (au[j] > p && au[j] < mn) mn = au[j];
  for (int m = 1; m <= 32; m <<= 1) {
    unsigned long long o = __shfl_xor(mn, m, 64);
    if (o < mn) mn = o;
  }
  int idx2 = -1;
#pragma unroll
  for (int j = 0; j < 4; ++j)
    if (au[j] == mn && kk[j] < K) idx2 = kk[j];
  for (int m = 1; m <= 32; m <<= 1) idx2 = max(idx2, __shfl_xor(idx2, m, 64));

#pragma unroll
  for (int j = 0; j < 4; ++j) {
    if (kk[j] < K) {
      float fv = (au[j] > p) ? (float)f[j] : 0.f;
      __hip_bfloat16 hb = __float2bfloat16(fv);
      *(short*)(featb + tb_addr(r, kk[j])) = *(short*)&hb;
    }
  }
  if (lane == 0) {
    double gap = __longlong_as_double((long long)mn) -
                 __longlong_as_double((long long)p);
    exgap[bid] = (unsigned long long)__double_as_longlong(gap);
    exidx2[bid] = idx2;
  }
}

// ---------------------------------------------------------------------------
// Tie fixup: zero the kept-min element on the global argmin-gap row.
// ---------------------------------------------------------------------------
__global__ void tiefix_kernel(const int* __restrict__ fragcnt,
                              const int* __restrict__ fraglist,
                              const unsigned long long* __restrict__ exgap,
                              const int* __restrict__ exidx2,
                              char* __restrict__ featb, int K) {
  int n = *fragcnt; if (n > MAXFRAG) n = MAXFRAG;
  if (n <= 0) return;
  const int lane = threadIdx.x;
  unsigned long long best = 0xFFFFFFFFFFFFFFFFull; int bi = -1;
  for (int i = lane; i < n; i += 64) {
    unsigned long long g = exgap[i];
    if (g < best) { best = g; bi = i; }
  }
  for (int m = 1; m <= 32; m <<= 1) {
    unsigned long long ob = __shfl_xor(best, m, 64);
    int oi = __shfl_xor(bi, m, 64);
    if (ob < best || (ob == best && oi >= 0 && (bi < 0 || oi < bi))) {
      best = ob; bi = oi;
    }
  }
  if (lane == 0 && bi >= 0) {
    int r = fraglist[bi];
    int idx = exidx2[bi];
    if (idx >= 0 && idx < K) *(short*)(featb + tb_addr(r, idx)) = 0;
  }
}

// ---------------------------------------------------------------------------
// GEMM2 via bf16 MFMA, K-split staging, XCD-swizzled 1D grid (4096 % 8 == 0).
// ---------------------------------------------------------------------------
__global__ __launch_bounds__(256, 5) void gemm2_mfma_kernel(
    const char* __restrict__ featb, const char* __restrict__ fcwb,
    const float* __restrict__ fcb, float* __restrict__ out,
    int B, int NC, int nct) {
  const int total = gridDim.x;
  const int cpx = total >> 3;
  const int bid = (int)blockIdx.x;
  const int swz = ((total & 7) == 0) ? (bid & 7) * cpx + (bid >> 3) : bid;
  const int by = swz / nct;
  const int bx = swz % nct;

  __shared__ __align__(16) char smem2[32768];
  char* a_s = smem2;
  char* b_s = smem2 + 16384;

  const int t = threadIdx.x;
  const int lane = t & 63;
  const int w = t >> 6;
  const int wr = w & 1, wc = w >> 1;
  const int lm = lane & 15;
  const int qlane = lane >> 4;
  const int r0 = by * 64;
  const int c0 = bx * 64;

  const char* ga = featb + (size_t)by * 32768;
  const char* gb = fcwb + (size_t)bx * 32768;

  f32x4 acc[2][2];
#pragma unroll
  for (int i = 0; i < 2; ++i)
#pragma unroll
    for (int j = 0; j < 2; ++j) acc[i][j] = (f32x4)(0.0f);

  const int ar = 32 * wr + lm, br = 32 * wc + lm;
  const int swa = (ar & 7) << 4, swb = (br & 7) << 4;
  const int lrow = lane >> 4;
  const int lbyt = (lane & 15) * 16;

  for (int kc = 0; kc < 2; ++kc) {
    if (kc) __syncthreads();
#pragma unroll
    for (int j = 0; j < 4; ++j) {
      const int call = w * 4 + j;
      const int row = call * 4 + lrow;
      const size_t goff = (size_t)row * 512 + (size_t)kc * 256 + lbyt;
      __builtin_amdgcn_global_load_lds(
          (const __attribute__((address_space(1))) unsigned int*)(ga + goff),
          (__attribute__((address_space(3))) unsigned int*)(a_s + call * 1024),
          16, 0, 0);
      __builtin_amdgcn_global_load_lds(
          (const __attribute__((address_space(1))) unsigned int*)(gb + goff),
          (__attribute__((address_space(3))) unsigned int*)(b_s + call * 1024),
          16, 0, 0);
    }
    __syncthreads();

    const int nch = kc ? 3 : 4;
#pragma unroll
    for (int ch = 0; ch < 4; ++ch) {
      if (ch >= nch) break;
      const int ql = ch * 4 + qlane;
      short8v ar0 = *(const short8v*)(a_s + ar * 256 + ((ql * 16) ^ swa));
      short8v ar1 = *(const short8v*)(a_s + (ar + 16) * 256 + ((ql * 16) ^ swa));
      short8v br0 = *(const short8v*)(b_s + br * 256 + ((ql * 16) ^ swb));
      short8v br1 = *(const short8v*)(b_s + (br + 16) * 256 + ((ql * 16) ^ swb));
      acc[0][0] = __builtin_amdgcn_mfma_f32_16x16x32_bf16(ar0, br0, acc[0][0], 0, 0, 0);
      acc[0][1] = __builtin_amdgcn_mfma_f32_16x16x32_bf16(ar0, br1, acc[0][1], 0, 0, 0);
      acc[1][0] = __builtin_amdgcn_mfma_f32_16x16x32_bf16(ar1, br0, acc[1][0], 0, 0, 0);
      acc[1][1] = __builtin_amdgcn_mfma_f32_16x16x32_bf16(ar1, br1, acc[1][1], 0, 0, 0);
    }
  }

#pragma unroll
  for (int rt = 0; rt < 2; ++rt) {
    const int row = r0 + 32 * wr + 16 * rt + (lane >> 4) * 4;
#pragma unroll
    for (int ct = 0; ct < 2; ++ct) {
      const int col = c0 + 32 * wc + 16 * ct + lm;
      if (col < NC) {
        const float bb = fcb[col];
#pragma unroll
        for (int r = 0; r < 4; ++r)
          out[(size_t)(row + r) * NC + col] = acc[rt][ct][r] + bb;
      }
    }
  }
}

// ---------------------------------------------------------------------------
extern "C" void kernel_launch(void* const* d_in, const int* in_sizes, int n_in,
                              void* d_out, int out_size, void* d_ws, size_t ws_size,
                              hipStream_t stream) {
  const float* x        = (const float*)d_in[0];
  const float* concepts = (const float*)d_in[1];
  const float* lnw      = (const float*)d_in[2];
  const float* lnb      = (const float*)d_in[3];
  const float* fcw      = (const float*)d_in[4];
  const float* fcb      = (const float*)d_in[5];
  const int*   feat_idx = (const int*)d_in[6];

  const int K  = in_sizes[2];        // 200
  const int C  = in_sizes[1] / K;    // 2048
  const int B  = in_sizes[0] / C;    // 16384
  const int NC = in_sizes[5];        // 1000
  const int NCT = (NC + 63) / 64;    // 16

  char* wsp = (char*)d_ws;
  short* ptile = (short*)wsp;  wsp += (size_t)64 * PT_BYTES;       // 1.7 MB
  double* pt64k = (double*)wsp; wsp += (size_t)KP * C * 8;         // 3.4 MB
  char* featb = wsp;  wsp += (size_t)(B / 64) * 32768;             // 8.4 MB
  char* fcwb = wsp;   wsp += (size_t)NCT * 32768;                  // 512 KB
  int* fragcnt = (int*)wsp;   wsp += 256;
  int* fraglist = (int*)wsp;  wsp += MAXFRAG * 4;
  unsigned long long* exgap = (unsigned long long*)wsp; wsp += MAXFRAG * 8;
  int* exidx2 = (int*)wsp;    wsp += MAXFRAG * 4;
  double* rowdots = (double*)wsp; wsp += (size_t)MAXFRAG * KP * 8;
  float* pfeat = (float*)wsp;  // B * NSLICE * KP * 4 = 27.3 MB

  l2norm_all_kernel<<<dim3(KP, 4), 256, 0, stream>>>(concepts, ptile, pt64k, C, K);
  fcw_bf16_kernel<<<NCT * 64, 256, 0, stream>>>(fcw, fcwb, fragcnt, K, NC);
  gemm1_mfma_partial_kernel<<<dim3(B / 32, NSLICE), 256, 0, stream>>>(
      x, ptile, pfeat, B, C, C / NSLICE);
  combine_ln_flag_kernel<<<B / 32, 256, 0, stream>>>(
      pfeat, lnw, lnb, feat_idx, featb, fraglist, fragcnt, B, K);
  recompute_dots_kernel<<<dim3(MAXFRAG, KP / 16), 256, 0, stream>>>(
      x, pt64k, fraglist, fragcnt, rowdots, C);
  recompute_ln_kernel<<<MAXFRAG, 64, 0, stream>>>(
      rowdots, lnw, lnb, feat_idx, fraglist, fragcnt, featb, exgap, exidx2, K);
  tiefix_kernel<<<1, 64, 0, stream>>>(fragcnt, fraglist, exgap, exidx2, featb, K);
  gemm2_mfma_kernel<<<NCT * (B / 64), 256, 0, stream>>>(
      featb, fcwb, fcb, (float*)d_out, B, NC, NCT);
}